// Round 2
// baseline (759.586 us; speedup 1.0000x reference)
//
#include <hip/hip_runtime.h>
#include <math.h>

#define NEGSLOPE 0.2f

__device__ __forceinline__ float lrelu(float x) { return x > 0.f ? x : NEGSLOPE * x; }

// ---------------- CSR build ----------------
__global__ void k_initdeg(int* __restrict__ deg, int n) {
    int i = blockIdx.x * 256 + threadIdx.x;
    if (i < n) deg[i] = 1;   // self loop contributes 1 in-edge per node
}
__global__ void k_count(const int* __restrict__ tgt, int* __restrict__ deg, int e) {
    int i = blockIdx.x * 256 + threadIdx.x;
    if (i < e) atomicAdd(&deg[tgt[i]], 1);
}
// block scans 4096 elements (256 threads x 16)
__global__ __launch_bounds__(256) void k_scanA(const int* __restrict__ deg, int* __restrict__ rowptr,
                                               int* __restrict__ bsums, int n) {
    __shared__ int s[256];
    int t = threadIdx.x;
    int base = blockIdx.x * 4096 + t * 16;
    int pre[16];
    int sum = 0;
    for (int i = 0; i < 16; ++i) {
        int idx = base + i;
        int v = (idx < n) ? deg[idx] : 0;
        pre[i] = sum;
        sum += v;
    }
    s[t] = sum;
    __syncthreads();
    for (int off = 1; off < 256; off <<= 1) {
        int v = (t >= off) ? s[t - off] : 0;
        __syncthreads();
        s[t] += v;
        __syncthreads();
    }
    int tbase = s[t] - sum;   // exclusive base for this thread within block
    for (int i = 0; i < 16; ++i) {
        int idx = base + i;
        if (idx < n) rowptr[idx] = tbase + pre[i];
    }
    if (t == 0) bsums[blockIdx.x] = s[255];
}
__global__ void k_scanB(int* __restrict__ bsums, int* __restrict__ rowptr, int nblk, int n) {
    if (threadIdx.x == 0 && blockIdx.x == 0) {
        int run = 0;
        for (int i = 0; i < nblk; ++i) { int v = bsums[i]; bsums[i] = run; run += v; }
        rowptr[n] = run;   // Etot
    }
}
__global__ void k_scanC(int* __restrict__ rowptr, const int* __restrict__ bsums, int n) {
    int i = blockIdx.x * 256 + threadIdx.x;
    if (i < n) rowptr[i] += bsums[i >> 12];   // 4096 per scan block
}
__global__ void k_self(const int* __restrict__ rowptr, int* __restrict__ edst, int* __restrict__ cursor, int n) {
    int i = blockIdx.x * 256 + threadIdx.x;
    if (i < n) { int p = rowptr[i]; edst[p] = i; cursor[i] = p + 1; }
}
__global__ void k_scatter(const int* __restrict__ src, const int* __restrict__ tgt,
                          int* __restrict__ cursor, int* __restrict__ edst, int e) {
    int i = blockIdx.x * 256 + threadIdx.x;
    if (i < e) { int p = atomicAdd(&cursor[tgt[i]], 1); edst[p] = src[i]; }
}

// ---------------- fp32 GEMM: out[n,kout] = A[n,128] @ W[128,kout] ----------------
// 64x64 tile, 4x4 register micro-tile per thread, K=128 staged fully in LDS.
__global__ __launch_bounds__(256) void k_gemm128(const float* __restrict__ A, const float* __restrict__ W,
                                                 float* __restrict__ out, int n, int kout) {
    __shared__ float As[64][129];   // +1 pad: compute reads hit 4 distinct banks
    __shared__ float Ws[128][64];
    int t = threadIdx.x;
    int row0 = blockIdx.x * 64;
    int c0 = blockIdx.y * 64;
    // load A tile (64 rows x 128 cols), float4, coalesced
    for (int i = 0; i < 8; ++i) {
        int idx = t + 256 * i;          // quad index
        int r = idx >> 5;               // 0..63
        int kq = idx & 31;              // 0..31
        float4 v = make_float4(0.f, 0.f, 0.f, 0.f);
        int gr = row0 + r;
        if (gr < n) v = *(const float4*)(A + (size_t)gr * 128 + 4 * kq);
        As[r][4 * kq + 0] = v.x; As[r][4 * kq + 1] = v.y;
        As[r][4 * kq + 2] = v.z; As[r][4 * kq + 3] = v.w;
    }
    // load W tile (128 x 64), float4, coalesced
    for (int i = 0; i < 8; ++i) {
        int idx = t + 256 * i;
        int k = idx >> 4;               // 0..127
        int cq = idx & 15;              // 0..15
        float4 v = *(const float4*)(W + (size_t)k * kout + c0 + 4 * cq);
        *(float4*)&Ws[k][4 * cq] = v;
    }
    __syncthreads();
    int tx = t & 15, ty = t >> 4;
    int r0 = ty * 4, cl = tx * 4;
    float acc[4][4] = {};
#pragma unroll 4
    for (int k = 0; k < 128; ++k) {
        float a0 = As[r0 + 0][k], a1 = As[r0 + 1][k], a2 = As[r0 + 2][k], a3 = As[r0 + 3][k];
        float4 wv = *(const float4*)&Ws[k][cl];
        acc[0][0] += a0 * wv.x; acc[0][1] += a0 * wv.y; acc[0][2] += a0 * wv.z; acc[0][3] += a0 * wv.w;
        acc[1][0] += a1 * wv.x; acc[1][1] += a1 * wv.y; acc[1][2] += a1 * wv.z; acc[1][3] += a1 * wv.w;
        acc[2][0] += a2 * wv.x; acc[2][1] += a2 * wv.y; acc[2][2] += a2 * wv.z; acc[2][3] += a2 * wv.w;
        acc[3][0] += a3 * wv.x; acc[3][1] += a3 * wv.y; acc[3][2] += a3 * wv.z; acc[3][3] += a3 * wv.w;
    }
    for (int j = 0; j < 4; ++j) {
        int gr = row0 + r0 + j;
        if (gr < n) {
            float4 o = make_float4(acc[j][0], acc[j][1], acc[j][2], acc[j][3]);
            *(float4*)(out + (size_t)gr * kout + c0 + cl) = o;
        }
    }
}

// ---------------- GATv2 aggregation: wave per node, online softmax ----------------
// H heads x C chans; F = H*C in {128, 64}. Lane holds VEC=F/64 consecutive channels.
template<int H, int C>
__global__ __launch_bounds__(256) void k_agg(const float* __restrict__ xl, const float* __restrict__ xr,
                                             const float* __restrict__ att, const float* __restrict__ bias,
                                             const int* __restrict__ rowptr, const int* __restrict__ edst,
                                             float* __restrict__ yout, int n) {
    constexpr int F = H * C;
    constexpr int VEC = F / 64;      // 2 (128) or 1 (64)
    constexpr int L = C / VEC;       // lanes per head group: 16 or 64
    int lane = threadIdx.x & 63;
    int node = blockIdx.x * 4 + (threadIdx.x >> 6);
    if (node >= n) return;           // wave-uniform exit
    int ch = lane * VEC;
    float u[VEC], av[VEC], acc[VEC];
#pragma unroll
    for (int j = 0; j < VEC; ++j) {
        u[j] = xr[(size_t)node * F + ch + j];
        av[j] = att[ch + j];
        acc[j] = 0.f;
    }
    float m = -INFINITY, ssum = 0.f;
    int e0 = rowptr[node], e1 = rowptr[node + 1];
    for (int e = e0; e < e1; ++e) {
        int src = edst[e];
        float v[VEC];
        if constexpr (VEC == 2) {
            float2 t2 = *(const float2*)(xl + (size_t)src * F + ch);
            v[0] = t2.x; v[1] = t2.y;
        } else {
            v[0] = xl[(size_t)src * F + ch];
        }
        float p = 0.f;
#pragma unroll
        for (int j = 0; j < VEC; ++j) {
            float g = v[j] + u[j];
            g = lrelu(g);
            p += g * av[j];
        }
#pragma unroll
        for (int off = 1; off < L; off <<= 1)
            p += __shfl_xor(p, off);
        // online softmax update
        float mnew = fmaxf(m, p);
        float scale = __expf(m - mnew);   // first iter: exp(-inf)=0
        float w = __expf(p - mnew);
        ssum = ssum * scale + w;
#pragma unroll
        for (int j = 0; j < VEC; ++j) acc[j] = acc[j] * scale + w * v[j];
        m = mnew;
    }
    float inv = 1.f / ssum;
#pragma unroll
    for (int j = 0; j < VEC; ++j) {
        float o = acc[j] * inv + bias[ch + j];
        yout[(size_t)node * F + ch + j] = lrelu(o);
    }
}

// ---------------- global mean pool (batch sorted -> binary-search ranges) ----------------
__global__ __launch_bounds__(256) void k_pool(const float* __restrict__ y, const int* __restrict__ batch,
                                              float* __restrict__ out, int n) {
    __shared__ float sdata[256];
    __shared__ int range[2];
    int g = blockIdx.x;
    int t = threadIdx.x;
    if (t == 0) {
        int lo = 0, hi = n;
        while (lo < hi) { int mid = (lo + hi) >> 1; if (batch[mid] < g) lo = mid + 1; else hi = mid; }
        range[0] = lo;
        hi = n;
        while (lo < hi) { int mid = (lo + hi) >> 1; if (batch[mid] < g + 1) lo = mid + 1; else hi = mid; }
        range[1] = lo;
    }
    __syncthreads();
    int start = range[0], end = range[1];
    int ch = t & 63, sub = t >> 6;
    float acc = 0.f;
    for (int node = start + sub; node < end; node += 4)
        acc += y[(size_t)node * 64 + ch];
    sdata[t] = acc;
    __syncthreads();
    if (t < 128) sdata[t] += sdata[t + 128];
    __syncthreads();
    if (t < 64) {
        float s = sdata[t] + sdata[t + 64];
        float cnt = (float)(end - start);
        out[g * 64 + t] = s / fmaxf(cnt, 1.f);
    }
}

extern "C" void kernel_launch(void* const* d_in, const int* in_sizes, int n_in,
                              void* d_out, int out_size, void* d_ws, size_t ws_size,
                              hipStream_t stream) {
    const float* x     = (const float*)d_in[0];
    const int*   ei    = (const int*)d_in[1];
    const int*   batch = (const int*)d_in[2];
    const float* Wl0 = (const float*)d_in[3];
    const float* Wr0 = (const float*)d_in[4];
    const float* att0 = (const float*)d_in[5];
    const float* b0  = (const float*)d_in[6];
    const float* Wl1 = (const float*)d_in[7];
    const float* Wr1 = (const float*)d_in[8];
    const float* att1 = (const float*)d_in[9];
    const float* b1  = (const float*)d_in[10];
    const float* Wl2 = (const float*)d_in[11];
    const float* Wr2 = (const float*)d_in[12];
    const float* att2 = (const float*)d_in[13];
    const float* b2  = (const float*)d_in[14];

    const int N = in_sizes[2];        // 50000
    const int E = in_sizes[1] / 2;    // 800000
    const int G = out_size / 64;      // 64
    const int* src = ei;
    const int* tgt = ei + E;

    // workspace layout (all 256B aligned)
    size_t off = 0;
    auto take = [&](size_t bytes) {
        void* p = (char*)d_ws + off;
        off = (off + bytes + 255) & ~(size_t)255;
        return p;
    };
    float* A    = (float*)take((size_t)N * 128 * 4);   // xl
    float* B    = (float*)take((size_t)N * 128 * 4);   // xr
    float* Cb   = (float*)take((size_t)N * 128 * 4);   // layer output / next input
    int* rowptr = (int*)take((size_t)(N + 1) * 4);
    int* tmp    = (int*)take((size_t)N * 4);           // deg, then cursor
    int* edst   = (int*)take((size_t)(E + N) * 4);
    int* bsums  = (int*)take(64 * 4);
    (void)ws_size; (void)n_in;

    const int TB = 256;
    int nblkN = (N + TB - 1) / TB;
    int nblkE = (E + TB - 1) / TB;
    int nscan = (N + 4095) / 4096;

    // --- CSR build (same topology for all layers) ---
    k_initdeg<<<nblkN, TB, 0, stream>>>(tmp, N);
    k_count<<<nblkE, TB, 0, stream>>>(tgt, tmp, E);
    k_scanA<<<nscan, TB, 0, stream>>>(tmp, rowptr, bsums, N);
    k_scanB<<<1, 64, 0, stream>>>(bsums, rowptr, nscan, N);
    k_scanC<<<nblkN, TB, 0, stream>>>(rowptr, bsums, N);
    k_self<<<nblkN, TB, 0, stream>>>(rowptr, edst, tmp, N);
    k_scatter<<<nblkE, TB, 0, stream>>>(src, tgt, tmp, edst, E);

    dim3 gemmGrid2((N + 63) / 64, 2);   // kout=128
    dim3 gemmGrid1((N + 63) / 64, 1);   // kout=64
    int aggBlocks = (N + 3) / 4;

    // --- layer 0: x[ N,128 ] -> Cb[ N,128 ] ---
    k_gemm128<<<gemmGrid2, TB, 0, stream>>>(x, Wl0, A, N, 128);
    k_gemm128<<<gemmGrid2, TB, 0, stream>>>(x, Wr0, B, N, 128);
    k_agg<4, 32><<<aggBlocks, TB, 0, stream>>>(A, B, att0, b0, rowptr, edst, Cb, N);

    // --- layer 1: Cb -> Cb ---
    k_gemm128<<<gemmGrid2, TB, 0, stream>>>(Cb, Wl1, A, N, 128);
    k_gemm128<<<gemmGrid2, TB, 0, stream>>>(Cb, Wr1, B, N, 128);
    k_agg<4, 32><<<aggBlocks, TB, 0, stream>>>(A, B, att1, b1, rowptr, edst, Cb, N);

    // --- layer 2: Cb[N,128] -> Cb[N,64] ---
    k_gemm128<<<gemmGrid1, TB, 0, stream>>>(Cb, Wl2, A, N, 64);
    k_gemm128<<<gemmGrid1, TB, 0, stream>>>(Cb, Wr2, B, N, 64);
    k_agg<1, 64><<<aggBlocks, TB, 0, stream>>>(A, B, att2, b2, rowptr, edst, Cb, N);

    // --- global mean pool ---
    k_pool<<<G, TB, 0, stream>>>(Cb, batch, (float*)d_out, N);
}

// Round 3
// 594.223 us; speedup vs baseline: 1.2783x; 1.2783x over previous
//
#include <hip/hip_runtime.h>
#include <math.h>

#define NEGSLOPE 0.2f

__device__ __forceinline__ float lrelu(float x) { return x > 0.f ? x : NEGSLOPE * x; }

// ---------------- CSR build ----------------
__global__ void k_initdeg(int* __restrict__ deg, int n) {
    int i = blockIdx.x * 256 + threadIdx.x;
    if (i < n) deg[i] = 1;   // self loop contributes 1 in-edge per node
}
__global__ void k_count(const int* __restrict__ tgt, int* __restrict__ deg, int e) {
    int i = blockIdx.x * 256 + threadIdx.x;
    if (i < e) atomicAdd(&deg[tgt[i]], 1);
}
// block scans 4096 elements (256 threads x 16)
__global__ __launch_bounds__(256) void k_scanA(const int* __restrict__ deg, int* __restrict__ rowptr,
                                               int* __restrict__ bsums, int n) {
    __shared__ int s[256];
    int t = threadIdx.x;
    int base = blockIdx.x * 4096 + t * 16;
    int pre[16];
    int sum = 0;
    for (int i = 0; i < 16; ++i) {
        int idx = base + i;
        int v = (idx < n) ? deg[idx] : 0;
        pre[i] = sum;
        sum += v;
    }
    s[t] = sum;
    __syncthreads();
    for (int off = 1; off < 256; off <<= 1) {
        int v = (t >= off) ? s[t - off] : 0;
        __syncthreads();
        s[t] += v;
        __syncthreads();
    }
    int tbase = s[t] - sum;   // exclusive base for this thread within block
    for (int i = 0; i < 16; ++i) {
        int idx = base + i;
        if (idx < n) rowptr[idx] = tbase + pre[i];
    }
    if (t == 0) bsums[blockIdx.x] = s[255];
}
__global__ void k_scanB(int* __restrict__ bsums, int* __restrict__ rowptr, int nblk, int n) {
    if (threadIdx.x == 0 && blockIdx.x == 0) {
        int run = 0;
        for (int i = 0; i < nblk; ++i) { int v = bsums[i]; bsums[i] = run; run += v; }
        rowptr[n] = run;   // Etot
    }
}
__global__ void k_scanC(int* __restrict__ rowptr, const int* __restrict__ bsums, int n) {
    int i = blockIdx.x * 256 + threadIdx.x;
    if (i < n) rowptr[i] += bsums[i >> 12];   // 4096 per scan block
}
__global__ void k_self(const int* __restrict__ rowptr, int* __restrict__ edst, int* __restrict__ cursor, int n) {
    int i = blockIdx.x * 256 + threadIdx.x;
    if (i < n) { int p = rowptr[i]; edst[p] = i; cursor[i] = p + 1; }
}
__global__ void k_scatter(const int* __restrict__ src, const int* __restrict__ tgt,
                          int* __restrict__ cursor, int* __restrict__ edst, int e) {
    int i = blockIdx.x * 256 + threadIdx.x;
    if (i < e) { int p = atomicAdd(&cursor[tgt[i]], 1); edst[p] = src[i]; }
}

// ---------------- fused fp32 GEMM: out0 = A@W0, out1 = A@W1 (W: [128,KOUT]) ----
// 64-row block; A tile staged ONCE in LDS, reused across 2*KOUT/64 column tiles.
template<int KOUT>
__global__ __launch_bounds__(256) void k_gemm_fused(const float* __restrict__ Ain,
        const float* __restrict__ W0, const float* __restrict__ W1,
        float* __restrict__ out0, float* __restrict__ out1, int n) {
    constexpr int CTW = KOUT / 64;           // column tiles per weight matrix
    __shared__ float As[64][129];            // +1 pad: a-reads broadcast on 4 distinct banks
    __shared__ float Ws[128][64];
    int t = threadIdx.x;
    int row0 = blockIdx.x * 64;
    for (int i = 0; i < 8; ++i) {
        int idx = t + 256 * i;
        int r = idx >> 5, kq = idx & 31;
        float4 v = make_float4(0.f, 0.f, 0.f, 0.f);
        int gr = row0 + r;
        if (gr < n) v = *(const float4*)(Ain + (size_t)gr * 128 + 4 * kq);
        As[r][4 * kq + 0] = v.x; As[r][4 * kq + 1] = v.y;
        As[r][4 * kq + 2] = v.z; As[r][4 * kq + 3] = v.w;
    }
    int tx = t & 15, ty = t >> 4;
    int r0 = ty * 4, cl = tx * 4;
    for (int ct = 0; ct < 2 * CTW; ++ct) {
        const float* W = (ct < CTW) ? W0 : W1;
        float* out = (ct < CTW) ? out0 : out1;
        int c0 = (ct & (CTW - 1)) * 64;
        __syncthreads();                     // As ready (first iter) / Ws drained (later)
        for (int i = 0; i < 8; ++i) {
            int idx = t + 256 * i;
            int k = idx >> 4, cq = idx & 15;
            *(float4*)&Ws[k][4 * cq] = *(const float4*)(W + (size_t)k * KOUT + c0 + 4 * cq);
        }
        __syncthreads();
        float acc[4][4] = {};
#pragma unroll 8
        for (int k = 0; k < 128; ++k) {
            float a0 = As[r0 + 0][k], a1 = As[r0 + 1][k], a2 = As[r0 + 2][k], a3 = As[r0 + 3][k];
            float4 wv = *(const float4*)&Ws[k][cl];
            acc[0][0] += a0 * wv.x; acc[0][1] += a0 * wv.y; acc[0][2] += a0 * wv.z; acc[0][3] += a0 * wv.w;
            acc[1][0] += a1 * wv.x; acc[1][1] += a1 * wv.y; acc[1][2] += a1 * wv.z; acc[1][3] += a1 * wv.w;
            acc[2][0] += a2 * wv.x; acc[2][1] += a2 * wv.y; acc[2][2] += a2 * wv.z; acc[2][3] += a2 * wv.w;
            acc[3][0] += a3 * wv.x; acc[3][1] += a3 * wv.y; acc[3][2] += a3 * wv.z; acc[3][3] += a3 * wv.w;
        }
        for (int j = 0; j < 4; ++j) {
            int gr = row0 + r0 + j;
            if (gr < n)
                *(float4*)(out + (size_t)gr * KOUT + c0 + cl) =
                    make_float4(acc[j][0], acc[j][1], acc[j][2], acc[j][3]);
        }
    }
}

// ---------------- GATv2 aggregation: wave per node ----------------
// No max-subtraction (scores bounded; exp(p)/sum exp(p) == reference softmax).
// Adjacency chunk loaded with ONE coalesced load, indices broadcast via shfl.
// Edge loop unrolled x4 so 4 gathers are in flight.
template<int H, int C>
__global__ __launch_bounds__(256) void k_agg(const float* __restrict__ xl, const float* __restrict__ xr,
                                             const float* __restrict__ att, const float* __restrict__ bias,
                                             const int* __restrict__ rowptr, const int* __restrict__ edst,
                                             float* __restrict__ yout, int n) {
    constexpr int F = H * C;
    constexpr int VEC = F / 64;      // 2 (F=128) or 1 (F=64)
    constexpr int L = C / VEC;       // lanes per head group: 16 or 64
    int lane = threadIdx.x & 63;
    int node = blockIdx.x * 4 + (threadIdx.x >> 6);
    if (node >= n) return;           // wave-uniform exit
    int ch = lane * VEC;
    float u[VEC], av[VEC], acc[VEC];
#pragma unroll
    for (int j = 0; j < VEC; ++j) {
        u[j] = xr[(size_t)node * F + ch + j];
        av[j] = att[ch + j];
        acc[j] = 0.f;
    }
    float ssum = 0.f;
    int e0 = rowptr[node], deg = rowptr[node + 1] - e0;

    auto loadrow = [&](int s, float* v) {
        if constexpr (VEC == 2) {
            float2 t2 = *(const float2*)(xl + (size_t)s * F + ch);
            v[0] = t2.x; v[1] = t2.y;
        } else {
            v[0] = xl[(size_t)s * F + ch];
        }
    };
    auto dot = [&](const float* v) {
        float p = 0.f;
#pragma unroll
        for (int j = 0; j < VEC; ++j) p += lrelu(v[j] + u[j]) * av[j];
        return p;
    };

    for (int base = 0; base < deg; base += 64) {
        int cnt = deg - base; if (cnt > 64) cnt = 64;
        int idxreg = edst[e0 + base + ((lane < cnt) ? lane : 0)];
        int i = 0;
        for (; i + 4 <= cnt; i += 4) {
            int s0 = __shfl(idxreg, i + 0);
            int s1 = __shfl(idxreg, i + 1);
            int s2 = __shfl(idxreg, i + 2);
            int s3 = __shfl(idxreg, i + 3);
            float v0[VEC], v1[VEC], v2[VEC], v3[VEC];
            loadrow(s0, v0); loadrow(s1, v1); loadrow(s2, v2); loadrow(s3, v3);
            float p0 = dot(v0), p1 = dot(v1), p2 = dot(v2), p3 = dot(v3);
#pragma unroll
            for (int off = 1; off < L; off <<= 1) {
                p0 += __shfl_xor(p0, off);
                p1 += __shfl_xor(p1, off);
                p2 += __shfl_xor(p2, off);
                p3 += __shfl_xor(p3, off);
            }
            float w0 = __expf(p0), w1 = __expf(p1), w2 = __expf(p2), w3 = __expf(p3);
            ssum += (w0 + w1) + (w2 + w3);
#pragma unroll
            for (int j = 0; j < VEC; ++j)
                acc[j] += (w0 * v0[j] + w1 * v1[j]) + (w2 * v2[j] + w3 * v3[j]);
        }
        for (; i < cnt; ++i) {
            int s = __shfl(idxreg, i);
            float v[VEC];
            loadrow(s, v);
            float p = dot(v);
#pragma unroll
            for (int off = 1; off < L; off <<= 1) p += __shfl_xor(p, off);
            float w = __expf(p);
            ssum += w;
#pragma unroll
            for (int j = 0; j < VEC; ++j) acc[j] += w * v[j];
        }
    }
    float inv = 1.f / ssum;
#pragma unroll
    for (int j = 0; j < VEC; ++j) {
        float o = acc[j] * inv + bias[ch + j];
        yout[(size_t)node * F + ch + j] = lrelu(o);
    }
}

// ---------------- global mean pool (batch sorted -> binary-search ranges) ----------------
__global__ __launch_bounds__(256) void k_pool(const float* __restrict__ y, const int* __restrict__ batch,
                                              float* __restrict__ out, int n) {
    __shared__ float sdata[256];
    __shared__ int range[2];
    int g = blockIdx.x;
    int t = threadIdx.x;
    if (t == 0) {
        int lo = 0, hi = n;
        while (lo < hi) { int mid = (lo + hi) >> 1; if (batch[mid] < g) lo = mid + 1; else hi = mid; }
        range[0] = lo;
        hi = n;
        while (lo < hi) { int mid = (lo + hi) >> 1; if (batch[mid] < g + 1) lo = mid + 1; else hi = mid; }
        range[1] = lo;
    }
    __syncthreads();
    int start = range[0], end = range[1];
    int ch = t & 63, sub = t >> 6;
    float acc = 0.f;
    for (int node = start + sub; node < end; node += 4)
        acc += y[(size_t)node * 64 + ch];
    sdata[t] = acc;
    __syncthreads();
    if (t < 128) sdata[t] += sdata[t + 128];
    __syncthreads();
    if (t < 64) {
        float s = sdata[t] + sdata[t + 64];
        float cnt = (float)(end - start);
        out[g * 64 + t] = s / fmaxf(cnt, 1.f);
    }
}

extern "C" void kernel_launch(void* const* d_in, const int* in_sizes, int n_in,
                              void* d_out, int out_size, void* d_ws, size_t ws_size,
                              hipStream_t stream) {
    const float* x     = (const float*)d_in[0];
    const int*   ei    = (const int*)d_in[1];
    const int*   batch = (const int*)d_in[2];
    const float* Wl0 = (const float*)d_in[3];
    const float* Wr0 = (const float*)d_in[4];
    const float* att0 = (const float*)d_in[5];
    const float* b0  = (const float*)d_in[6];
    const float* Wl1 = (const float*)d_in[7];
    const float* Wr1 = (const float*)d_in[8];
    const float* att1 = (const float*)d_in[9];
    const float* b1  = (const float*)d_in[10];
    const float* Wl2 = (const float*)d_in[11];
    const float* Wr2 = (const float*)d_in[12];
    const float* att2 = (const float*)d_in[13];
    const float* b2  = (const float*)d_in[14];

    const int N = in_sizes[2];        // 50000
    const int E = in_sizes[1] / 2;    // 800000
    const int G = out_size / 64;      // 64
    const int* src = ei;
    const int* tgt = ei + E;

    // workspace layout (all 256B aligned)
    size_t off = 0;
    auto take = [&](size_t bytes) {
        void* p = (char*)d_ws + off;
        off = (off + bytes + 255) & ~(size_t)255;
        return p;
    };
    float* A    = (float*)take((size_t)N * 128 * 4);   // xl
    float* B    = (float*)take((size_t)N * 128 * 4);   // xr
    float* Cb   = (float*)take((size_t)N * 128 * 4);   // layer output / next input
    int* rowptr = (int*)take((size_t)(N + 1) * 4);
    int* tmp    = (int*)take((size_t)N * 4);           // deg, then cursor
    int* edst   = (int*)take((size_t)(E + N) * 4);
    int* bsums  = (int*)take(64 * 4);
    (void)ws_size; (void)n_in;

    const int TB = 256;
    int nblkN = (N + TB - 1) / TB;
    int nblkE = (E + TB - 1) / TB;
    int nscan = (N + 4095) / 4096;

    // --- CSR build (same topology for all layers) ---
    k_initdeg<<<nblkN, TB, 0, stream>>>(tmp, N);
    k_count<<<nblkE, TB, 0, stream>>>(tgt, tmp, E);
    k_scanA<<<nscan, TB, 0, stream>>>(tmp, rowptr, bsums, N);
    k_scanB<<<1, 64, 0, stream>>>(bsums, rowptr, nscan, N);
    k_scanC<<<nblkN, TB, 0, stream>>>(rowptr, bsums, N);
    k_self<<<nblkN, TB, 0, stream>>>(rowptr, edst, tmp, N);
    k_scatter<<<nblkE, TB, 0, stream>>>(src, tgt, tmp, edst, E);

    int gemmBlocks = (N + 63) / 64;
    int aggBlocks = (N + 3) / 4;

    // --- layer 0: x[N,128] -> Cb[N,128] ---
    k_gemm_fused<128><<<gemmBlocks, TB, 0, stream>>>(x, Wl0, Wr0, A, B, N);
    k_agg<4, 32><<<aggBlocks, TB, 0, stream>>>(A, B, att0, b0, rowptr, edst, Cb, N);

    // --- layer 1: Cb -> Cb ---
    k_gemm_fused<128><<<gemmBlocks, TB, 0, stream>>>(Cb, Wl1, Wr1, A, B, N);
    k_agg<4, 32><<<aggBlocks, TB, 0, stream>>>(A, B, att1, b1, rowptr, edst, Cb, N);

    // --- layer 2: Cb[N,128] -> Cb[N,64] ---
    k_gemm_fused<64><<<gemmBlocks, TB, 0, stream>>>(Cb, Wl2, Wr2, A, B, N);
    k_agg<1, 64><<<aggBlocks, TB, 0, stream>>>(A, B, att2, b2, rowptr, edst, Cb, N);

    // --- global mean pool ---
    k_pool<<<G, TB, 0, stream>>>(Cb, batch, (float*)d_out, N);
}

// Round 4
// 552.350 us; speedup vs baseline: 1.3752x; 1.0758x over previous
//
#include <hip/hip_runtime.h>
#include <math.h>

#define NEGSLOPE 0.2f

__device__ __forceinline__ float lrelu(float x) { return x > 0.f ? x : NEGSLOPE * x; }

// ---------------- CSR build ----------------
__global__ void k_initdeg(int* __restrict__ deg, int n) {
    int i = blockIdx.x * 256 + threadIdx.x;
    if (i < n) deg[i] = 1;   // self loop contributes 1 in-edge per node
}
__global__ void k_count(const int* __restrict__ tgt, int* __restrict__ deg, int e) {
    int i = blockIdx.x * 256 + threadIdx.x;
    if (i < e) atomicAdd(&deg[tgt[i]], 1);
}
// block scans 4096 elements (256 threads x 16)
__global__ __launch_bounds__(256) void k_scanA(const int* __restrict__ deg, int* __restrict__ rowptr,
                                               int* __restrict__ bsums, int n) {
    __shared__ int s[256];
    int t = threadIdx.x;
    int base = blockIdx.x * 4096 + t * 16;
    int pre[16];
    int sum = 0;
    for (int i = 0; i < 16; ++i) {
        int idx = base + i;
        int v = (idx < n) ? deg[idx] : 0;
        pre[i] = sum;
        sum += v;
    }
    s[t] = sum;
    __syncthreads();
    for (int off = 1; off < 256; off <<= 1) {
        int v = (t >= off) ? s[t - off] : 0;
        __syncthreads();
        s[t] += v;
        __syncthreads();
    }
    int tbase = s[t] - sum;   // exclusive base for this thread within block
    for (int i = 0; i < 16; ++i) {
        int idx = base + i;
        if (idx < n) rowptr[idx] = tbase + pre[i];
    }
    if (t == 0) bsums[blockIdx.x] = s[255];
}
__global__ void k_scanB(int* __restrict__ bsums, int* __restrict__ rowptr, int nblk, int n) {
    if (threadIdx.x == 0 && blockIdx.x == 0) {
        int run = 0;
        for (int i = 0; i < nblk; ++i) { int v = bsums[i]; bsums[i] = run; run += v; }
        rowptr[n] = run;   // Etot
    }
}
__global__ void k_scanC(int* __restrict__ rowptr, const int* __restrict__ bsums, int n) {
    int i = blockIdx.x * 256 + threadIdx.x;
    if (i < n) rowptr[i] += bsums[i >> 12];   // 4096 per scan block
}
__global__ void k_self(const int* __restrict__ rowptr, int* __restrict__ edst, int* __restrict__ cursor, int n) {
    int i = blockIdx.x * 256 + threadIdx.x;
    if (i < n) { int p = rowptr[i]; edst[p] = i; cursor[i] = p + 1; }
}
__global__ void k_scatter(const int* __restrict__ src, const int* __restrict__ tgt,
                          int* __restrict__ cursor, int* __restrict__ edst, int e) {
    int i = blockIdx.x * 256 + threadIdx.x;
    if (i < e) { int p = atomicAdd(&cursor[tgt[i]], 1); edst[p] = src[i]; }
}

// ---------------- fused fp32 GEMM: out0 = A@W0, out1 = A@W1 (W: [128,KOUT]) ----
// 64-row block; A tile staged ONCE in LDS, reused across 2*KOUT/64 column tiles.
// k-loop unrolled x4 with ds_read_b128 only (8 LDS instr per 64 FMA).
template<int KOUT>
__global__ __launch_bounds__(256) void k_gemm_fused(const float* __restrict__ Ain,
        const float* __restrict__ W0, const float* __restrict__ W1,
        float* __restrict__ out0, float* __restrict__ out1, int n) {
    constexpr int CTW = KOUT / 64;           // column tiles per weight matrix
    __shared__ float As[64][132];            // stride 132: 16B-aligned rows, bank-stagger
    __shared__ float Ws[128][64];
    int t = threadIdx.x;
    int row0 = blockIdx.x * 64;
    for (int i = 0; i < 8; ++i) {
        int idx = t + 256 * i;
        int r = idx >> 5, kq = idx & 31;
        float4 v = make_float4(0.f, 0.f, 0.f, 0.f);
        int gr = row0 + r;
        if (gr < n) v = *(const float4*)(Ain + (size_t)gr * 128 + 4 * kq);
        *(float4*)&As[r][4 * kq] = v;
    }
    int tx = t & 15, ty = t >> 4;
    int r0 = ty * 4, cl = tx * 4;
    for (int ct = 0; ct < 2 * CTW; ++ct) {
        const float* W = (ct < CTW) ? W0 : W1;
        float* out = (ct < CTW) ? out0 : out1;
        int c0 = (ct & (CTW - 1)) * 64;
        __syncthreads();                     // As ready (first iter) / Ws drained (later)
        for (int i = 0; i < 8; ++i) {
            int idx = t + 256 * i;
            int k = idx >> 4, cq = idx & 15;
            *(float4*)&Ws[k][4 * cq] = *(const float4*)(W + (size_t)k * KOUT + c0 + 4 * cq);
        }
        __syncthreads();
        float acc[4][4] = {};
#pragma unroll 2
        for (int k = 0; k < 128; k += 4) {
            float a_[4][4], w_[4][4];
#pragma unroll
            for (int j = 0; j < 4; ++j) *(float4*)a_[j] = *(const float4*)&As[r0 + j][k];
#pragma unroll
            for (int kk = 0; kk < 4; ++kk) *(float4*)w_[kk] = *(const float4*)&Ws[k + kk][cl];
#pragma unroll
            for (int kk = 0; kk < 4; ++kk)
#pragma unroll
                for (int j = 0; j < 4; ++j) {
                    acc[j][0] += a_[j][kk] * w_[kk][0];
                    acc[j][1] += a_[j][kk] * w_[kk][1];
                    acc[j][2] += a_[j][kk] * w_[kk][2];
                    acc[j][3] += a_[j][kk] * w_[kk][3];
                }
        }
        for (int j = 0; j < 4; ++j) {
            int gr = row0 + r0 + j;
            if (gr < n)
                *(float4*)(out + (size_t)gr * KOUT + c0 + cl) =
                    make_float4(acc[j][0], acc[j][1], acc[j][2], acc[j][3]);
        }
    }
}

// ---------------- GATv2 aggregation: 4 nodes per wave, 16 lanes per node ------
// Lane holds VEC = F/16 channels. Head spans L = C/VEC lanes (4 for H=4, 16 for H=1).
// 4 edges (one per node group) processed per instruction stream step; no max-
// subtraction (scores bounded -> exp(p)/sum exp(p) identical to ref softmax).
template<int H, int C>
__global__ __launch_bounds__(256) void k_agg(const float* __restrict__ xl, const float* __restrict__ xr,
                                             const float* __restrict__ att, const float* __restrict__ bias,
                                             const int* __restrict__ rowptr, const int* __restrict__ edst,
                                             float* __restrict__ yout, int n) {
    constexpr int F = H * C;
    constexpr int VEC = F / 16;      // 8 (F=128) or 4 (F=64)
    constexpr int L = C / VEC;       // lanes per head: 4 or 16
    int lane = threadIdx.x & 63;
    int wave = threadIdx.x >> 6;
    int s = lane & 15;               // sublane within node group
    int node = blockIdx.x * 16 + wave * 4 + (lane >> 4);
    bool valid = node < n;
    int nodeSafe = valid ? node : 0;
    int ch = s * VEC;

    float u[VEC], av[VEC], acc[VEC];
#pragma unroll
    for (int j = 0; j < VEC; ++j) {
        u[j] = xr[(size_t)nodeSafe * F + ch + j];
        av[j] = att[ch + j];
        acc[j] = 0.f;
    }
    int e0 = rowptr[nodeSafe];
    int deg = valid ? (rowptr[nodeSafe + 1] - e0) : 0;
    // wave-uniform max degree over the 4 node groups
    int maxdeg = deg;
    maxdeg = max(maxdeg, __shfl_xor(maxdeg, 16));
    maxdeg = max(maxdeg, __shfl_xor(maxdeg, 32));
    float ssum = 0.f;

    auto loadrow = [&](int src, float* v) {
        const float* p = xl + (size_t)src * F + ch;
        *(float4*)v = *(const float4*)p;
        if constexpr (VEC == 8) *(float4*)(v + 4) = *(const float4*)(p + 4);
    };
    auto edge = [&](int srcIdx, bool live) {
        float v[VEC];
        loadrow(srcIdx, v);
        float p = 0.f;
#pragma unroll
        for (int j = 0; j < VEC; ++j) p += lrelu(v[j] + u[j]) * av[j];
#pragma unroll
        for (int off = 1; off < L; off <<= 1) p += __shfl_xor(p, off);
        float w = live ? __expf(p) : 0.f;
        ssum += w;
#pragma unroll
        for (int j = 0; j < VEC; ++j) acc[j] += w * v[j];
    };

    for (int base = 0; base < maxdeg; base += 16) {
        int cnt = deg - base;                        // group-uniform
        if (cnt > 16) cnt = 16;
        int idxreg = (s < cnt) ? edst[e0 + base + s] : nodeSafe;
        int mcnt = cnt;                              // wave max for this chunk
        mcnt = max(mcnt, __shfl_xor(mcnt, 16));
        mcnt = max(mcnt, __shfl_xor(mcnt, 32));
        int gbase = lane & 48;                       // group<<4
        for (int i = 0; i < mcnt; i += 2) {
            int s0 = __shfl(idxreg, gbase + i);
            int s1 = __shfl(idxreg, gbase + i + 1);
            edge(s0, i < cnt);
            edge(s1, i + 1 < cnt);
        }
    }
    if (valid) {
        float inv = 1.f / ssum;
        float o[VEC];
#pragma unroll
        for (int j = 0; j < VEC; ++j) o[j] = lrelu(acc[j] * inv + bias[ch + j]);
        float* p = yout + (size_t)node * F + ch;
        *(float4*)p = *(float4*)o;
        if constexpr (VEC == 8) *(float4*)(p + 4) = *(float4*)(o + 4);
    }
}

// ---------------- global mean pool (batch sorted -> binary-search ranges) ----------------
__global__ __launch_bounds__(256) void k_pool(const float* __restrict__ y, const int* __restrict__ batch,
                                              float* __restrict__ out, int n) {
    __shared__ float sdata[256];
    __shared__ int range[2];
    int g = blockIdx.x;
    int t = threadIdx.x;
    if (t == 0) {
        int lo = 0, hi = n;
        while (lo < hi) { int mid = (lo + hi) >> 1; if (batch[mid] < g) lo = mid + 1; else hi = mid; }
        range[0] = lo;
        hi = n;
        while (lo < hi) { int mid = (lo + hi) >> 1; if (batch[mid] < g + 1) lo = mid + 1; else hi = mid; }
        range[1] = lo;
    }
    __syncthreads();
    int start = range[0], end = range[1];
    int ch = t & 63, sub = t >> 6;
    float acc = 0.f;
    for (int node = start + sub; node < end; node += 4)
        acc += y[(size_t)node * 64 + ch];
    sdata[t] = acc;
    __syncthreads();
    if (t < 128) sdata[t] += sdata[t + 128];
    __syncthreads();
    if (t < 64) {
        float s = sdata[t] + sdata[t + 64];
        float cnt = (float)(end - start);
        out[g * 64 + t] = s / fmaxf(cnt, 1.f);
    }
}

extern "C" void kernel_launch(void* const* d_in, const int* in_sizes, int n_in,
                              void* d_out, int out_size, void* d_ws, size_t ws_size,
                              hipStream_t stream) {
    const float* x     = (const float*)d_in[0];
    const int*   ei    = (const int*)d_in[1];
    const int*   batch = (const int*)d_in[2];
    const float* Wl0 = (const float*)d_in[3];
    const float* Wr0 = (const float*)d_in[4];
    const float* att0 = (const float*)d_in[5];
    const float* b0  = (const float*)d_in[6];
    const float* Wl1 = (const float*)d_in[7];
    const float* Wr1 = (const float*)d_in[8];
    const float* att1 = (const float*)d_in[9];
    const float* b1  = (const float*)d_in[10];
    const float* Wl2 = (const float*)d_in[11];
    const float* Wr2 = (const float*)d_in[12];
    const float* att2 = (const float*)d_in[13];
    const float* b2  = (const float*)d_in[14];

    const int N = in_sizes[2];        // 50000
    const int E = in_sizes[1] / 2;    // 800000
    const int G = out_size / 64;      // 64
    const int* src = ei;
    const int* tgt = ei + E;

    // workspace layout (all 256B aligned)
    size_t off = 0;
    auto take = [&](size_t bytes) {
        void* p = (char*)d_ws + off;
        off = (off + bytes + 255) & ~(size_t)255;
        return p;
    };
    float* A    = (float*)take((size_t)N * 128 * 4);   // xl
    float* B    = (float*)take((size_t)N * 128 * 4);   // xr
    float* Cb   = (float*)take((size_t)N * 128 * 4);   // layer output / next input
    int* rowptr = (int*)take((size_t)(N + 1) * 4);
    int* tmp    = (int*)take((size_t)N * 4);           // deg, then cursor
    int* edst   = (int*)take((size_t)(E + N) * 4);
    int* bsums  = (int*)take(64 * 4);
    (void)ws_size; (void)n_in;

    const int TB = 256;
    int nblkN = (N + TB - 1) / TB;
    int nblkE = (E + TB - 1) / TB;
    int nscan = (N + 4095) / 4096;

    // --- CSR build (same topology for all layers) ---
    k_initdeg<<<nblkN, TB, 0, stream>>>(tmp, N);
    k_count<<<nblkE, TB, 0, stream>>>(tgt, tmp, E);
    k_scanA<<<nscan, TB, 0, stream>>>(tmp, rowptr, bsums, N);
    k_scanB<<<1, 64, 0, stream>>>(bsums, rowptr, nscan, N);
    k_scanC<<<nblkN, TB, 0, stream>>>(rowptr, bsums, N);
    k_self<<<nblkN, TB, 0, stream>>>(rowptr, edst, tmp, N);
    k_scatter<<<nblkE, TB, 0, stream>>>(src, tgt, tmp, edst, E);

    int gemmBlocks = (N + 63) / 64;
    int aggBlocks = (N + 15) / 16;

    // --- layer 0: x[N,128] -> Cb[N,128] ---
    k_gemm_fused<128><<<gemmBlocks, TB, 0, stream>>>(x, Wl0, Wr0, A, B, N);
    k_agg<4, 32><<<aggBlocks, TB, 0, stream>>>(A, B, att0, b0, rowptr, edst, Cb, N);

    // --- layer 1: Cb -> Cb ---
    k_gemm_fused<128><<<gemmBlocks, TB, 0, stream>>>(Cb, Wl1, Wr1, A, B, N);
    k_agg<4, 32><<<aggBlocks, TB, 0, stream>>>(A, B, att1, b1, rowptr, edst, Cb, N);

    // --- layer 2: Cb[N,128] -> Cb[N,64] ---
    k_gemm_fused<64><<<gemmBlocks, TB, 0, stream>>>(Cb, Wl2, Wr2, A, B, N);
    k_agg<1, 64><<<aggBlocks, TB, 0, stream>>>(A, B, att2, b2, rowptr, edst, Cb, N);

    // --- global mean pool ---
    k_pool<<<G, TB, 0, stream>>>(Cb, batch, (float*)d_out, N);
}